// Round 17
// baseline (152.649 us; speedup 1.0000x reference)
//
#include <hip/hip_runtime.h>
#include <hip/hip_bf16.h>
#include <stdint.h>

typedef short  bf16x8 __attribute__((ext_vector_type(8)));
typedef float  f32x4  __attribute__((ext_vector_type(4)));
typedef unsigned short u16;

#define HD 16    // heads
#define DD 64    // head dim
#define BQ 128   // q rows per block (4 waves, 2 sub-tiles of 64: u-loop ILP, r12-validated)
#define BK 64    // keys per LDS tile

__device__ __forceinline__ u16 bf1(float a) {
  __hip_bfloat16 h = __float2bfloat16(a);
  union { __hip_bfloat16 h; u16 u; } cv; cv.h = h; return cv.u;
}
__device__ __forceinline__ uint32_t pk2(float a, float b) {
  __hip_bfloat162 h = __float22bfloat162_rn(make_float2(a, b)); // v_cvt_pk_bf16_f32
  union { __hip_bfloat162 h; uint32_t u; } cv; cv.h = h; return cv.u;
}

// K / P tiles: row-major [R][64] bf16, idx ^= (row&7)<<3
__device__ __forceinline__ bf16x8 ldsw8(const u16* base, int row, int col) {
  int idx = (row * 64 + col) ^ ((row & 7) << 3);
  return *reinterpret_cast<const bf16x8*>(base + idx);
}
// V^T tile: [d][key] bf16, idx ^= (((d>>2)^d)&7)<<3  (validated r11: conflicts 14x down)
__device__ __forceinline__ bf16x8 ldsv8(const u16* base, int d, int col) {
  int idx = (d * 64 + col) ^ ((((d >> 2) ^ d) & 7) << 3);
  return *reinterpret_cast<const bf16x8*>(base + idx);
}

__global__ __launch_bounds__(256) void fa_fwd(
    const float* __restrict__ q, const float* __restrict__ k,
    const float* __restrict__ v, const int* __restrict__ cu,
    float* __restrict__ out, int T, int nseq, int nqt)
{
  // double-buffered K/V tiles (56 KB total incl. sP)
  __shared__ __align__(16) u16 sKhi[2][BK * DD];
  __shared__ __align__(16) u16 sKlo[2][BK * DD];
  __shared__ __align__(16) u16 sVt [2][DD * BK];
  __shared__ __align__(16) u16 sP  [4][16 * BK];

  // ---- XCD-chunked bijective remap (m204) ----
  const int nwg = nqt * HD;
  const int x8 = blockIdx.x & 7, mm = blockIdx.x >> 3;
  const int q8 = nwg >> 3, r8 = nwg & 7;
  const int wid = (x8 < r8 ? x8 * (q8 + 1) : r8 * (q8 + 1) + (x8 - r8) * q8) + mm;
  const int h    = wid / nqt;
  const int tile = wid - h * nqt;

  // ---- map tile -> (segment, local q-tile) ----
  int seg = -1, row0 = 0, sbeg = 0, send = 0;
  {
    int acc = 0;
    for (int s = 0; s < nseq; ++s) {
      int b = cu[s], e = cu[s + 1];
      int nt = (e - b + BQ - 1) >> 7;
      if (seg < 0 && tile < acc + nt) {
        seg = s;
        int local = tile - acc;
        row0 = b + local * BQ; sbeg = b; send = e;
      }
      acc += nt;
    }
  }
  if (seg < 0) return;
  const int rows = min(BQ, send - row0);

  const int tid  = threadIdx.x;
  const int wv   = tid >> 6;
  const int lane = tid & 63;
  const int g    = lane >> 4;
  const int c    = lane & 15;

  // ---- Q fragments for both sub-tiles, scale+log2e, hi/lo split ----
  const float SC = 8.0f * 1.4426950408889634f;
  bf16x8 qhi[2][2], qlo[2][2];
  #pragma unroll
  for (int u = 0; u < 2; ++u) {
    const int qrl = min(u * 64 + wv * 16 + c, rows - 1);
    const float* qp = q + ((size_t)h * T + (row0 + qrl)) * DD;
    #pragma unroll
    for (int w = 0; w < 2; ++w) {
      int d0 = w * 32 + g * 8;
      float4 a = *reinterpret_cast<const float4*>(qp + d0);
      float4 b = *reinterpret_cast<const float4*>(qp + d0 + 4);
      float f[8] = {a.x, a.y, a.z, a.w, b.x, b.y, b.z, b.w};
      #pragma unroll
      for (int i = 0; i < 8; ++i) {
        float s  = f[i] * SC;
        u16   hb = bf1(s);
        float hf = __uint_as_float(((uint32_t)hb) << 16);
        qhi[u][w][i] = (short)hb;
        qlo[u][w][i] = (short)bf1(s - hf);
      }
    }
  }

  // staging thread assignment (256 threads)
  const int kd0  = (tid & 15) * 4;
  const int kkey = tid >> 4;
  const int vdg  = tid & 15;
  const int vkb  = tid >> 4;

  float4 kraw[4], vrawA[2], vrawB[2];   // in-flight next-tile registers

  auto issue_loads = [&](int kt0) {
    #pragma unroll
    for (int p = 0; p < 4; ++p) {
      int gk = kt0 + p * 16 + kkey; gk = gk < send ? gk : send - 1;
      kraw[p] = *reinterpret_cast<const float4*>(k + ((size_t)h * T + gk) * DD + kd0);
    }
    #pragma unroll
    for (int it = 0; it < 2; ++it) {
      int kp = it * 16 + vkb;
      int g0 = kt0 + 2 * kp;     g0 = g0 < send ? g0 : send - 1;
      int g1 = kt0 + 2 * kp + 1; g1 = g1 < send ? g1 : send - 1;
      vrawA[it] = *reinterpret_cast<const float4*>(v + ((size_t)h * T + g0) * DD + 4 * vdg);
      vrawB[it] = *reinterpret_cast<const float4*>(v + ((size_t)h * T + g1) * DD + 4 * vdg);
    }
  };
  auto cvt_write = [&](int b) {
    #pragma unroll
    for (int p = 0; p < 4; ++p) {
      int key = p * 16 + kkey;
      uint32_t h01 = pk2(kraw[p].x, kraw[p].y), h23 = pk2(kraw[p].z, kraw[p].w);
      float hf0 = __uint_as_float(h01 << 16);
      float hf1 = __uint_as_float(h01 & 0xffff0000u);
      float hf2 = __uint_as_float(h23 << 16);
      float hf3 = __uint_as_float(h23 & 0xffff0000u);
      uint32_t l01 = pk2(kraw[p].x - hf0, kraw[p].y - hf1);
      uint32_t l23 = pk2(kraw[p].z - hf2, kraw[p].w - hf3);
      int idx = (key * 64 + kd0) ^ ((key & 7) << 3);
      uint2 hh = {h01, h23}, ll = {l01, l23};
      *reinterpret_cast<uint2*>(&sKhi[b][0] + idx) = hh;
      *reinterpret_cast<uint2*>(&sKlo[b][0] + idx) = ll;
    }
    #pragma unroll
    for (int it = 0; it < 2; ++it) {
      int kp = it * 16 + vkb;
      float a[4] = {vrawA[it].x, vrawA[it].y, vrawA[it].z, vrawA[it].w};
      float bb[4] = {vrawB[it].x, vrawB[it].y, vrawB[it].z, vrawB[it].w};
      #pragma unroll
      for (int i = 0; i < 4; ++i) {
        int d   = 4 * vdg + i;
        int idx = (d * 64 + 2 * kp) ^ ((((d >> 2) ^ d) & 7) << 3);
        *reinterpret_cast<uint32_t*>(&sVt[b][0] + idx) = pk2(a[i], bb[i]);
      }
    }
  };

  f32x4 zero4 = {0.f, 0.f, 0.f, 0.f};
  f32x4 oacc[2][4];
  float mrun[2][4], lrun[2][4];
  #pragma unroll
  for (int u = 0; u < 2; ++u) {
    #pragma unroll
    for (int dt = 0; dt < 4; ++dt) oacc[u][dt] = zero4;
    #pragma unroll
    for (int j = 0; j < 4; ++j) { mrun[u][j] = -1e30f; lrun[u][j] = 0.f; }
  }

  const int nt = (send - sbeg + BK - 1) >> 6;

  // prologue: stage tile 0 into buffer 0
  issue_loads(sbeg);
  cvt_write(0);
  int cur = 0;

  for (int t = 0; t < nt; ++t) {
    const int kt0 = sbeg + t * BK;
    __syncthreads();   // buf[cur] ready; prior reads of buf[cur^1] complete
    const bool pre = (t + 1 < nt);
    if (pre) issue_loads(kt0 + BK);   // HBM latency hides under the compute below

    const u16* kh = sKhi[cur];
    const u16* kl = sKlo[cur];
    const u16* vt = sVt[cur];

    #pragma unroll
    for (int u = 0; u < 2; ++u) {
      f32x4 sacc[4];
      #pragma unroll
      for (int kt = 0; kt < 4; ++kt) sacc[kt] = zero4;
      #pragma unroll
      for (int kt = 0; kt < 4; ++kt) {
        int krow = kt * 16 + c;
        bf16x8 kh0 = ldsw8(kh, krow,      g * 8);
        bf16x8 kh1 = ldsw8(kh, krow, 32 + g * 8);
        bf16x8 kl0 = ldsw8(kl, krow,      g * 8);
        bf16x8 kl1 = ldsw8(kl, krow, 32 + g * 8);
        sacc[kt] = __builtin_amdgcn_mfma_f32_16x16x32_bf16(qhi[u][0], kh0, sacc[kt], 0, 0, 0);
        sacc[kt] = __builtin_amdgcn_mfma_f32_16x16x32_bf16(qhi[u][1], kh1, sacc[kt], 0, 0, 0);
        sacc[kt] = __builtin_amdgcn_mfma_f32_16x16x32_bf16(qlo[u][0], kh0, sacc[kt], 0, 0, 0);
        sacc[kt] = __builtin_amdgcn_mfma_f32_16x16x32_bf16(qlo[u][1], kh1, sacc[kt], 0, 0, 0);
        sacc[kt] = __builtin_amdgcn_mfma_f32_16x16x32_bf16(qhi[u][0], kl0, sacc[kt], 0, 0, 0);
        sacc[kt] = __builtin_amdgcn_mfma_f32_16x16x32_bf16(qhi[u][1], kl1, sacc[kt], 0, 0, 0);
      }

      if (kt0 + BK > send) {
        #pragma unroll
        for (int kt = 0; kt < 4; ++kt) {
          int gk = kt0 + kt * 16 + c;
          if (gk >= send) {
            sacc[kt][0] = -3.0e38f; sacc[kt][1] = -3.0e38f;
            sacc[kt][2] = -3.0e38f; sacc[kt][3] = -3.0e38f;
          }
        }
      }

      float mrow[4];
      #pragma unroll
      for (int j = 0; j < 4; ++j)
        mrow[j] = fmaxf(fmaxf(sacc[0][j], sacc[1][j]), fmaxf(sacc[2][j], sacc[3][j]));
      #pragma unroll
      for (int off = 1; off < 16; off <<= 1)
        #pragma unroll
        for (int j = 0; j < 4; ++j)
          mrow[j] = fmaxf(mrow[j], __shfl_xor(mrow[j], off, 64));

      float alpha[4];
      #pragma unroll
      for (int j = 0; j < 4; ++j) {
        float mn = fmaxf(mrun[u][j], mrow[j]);
        alpha[j] = exp2f(mrun[u][j] - mn);
        mrun[u][j] = mn;
      }

      float lrow[4] = {0.f, 0.f, 0.f, 0.f};
      u16* pb = sP[wv];
      #pragma unroll
      for (int kt = 0; kt < 4; ++kt) {
        int key = kt * 16 + c;
        #pragma unroll
        for (int j = 0; j < 4; ++j) {
          float pv = exp2f(sacc[kt][j] - mrun[u][j]);
          lrow[j] += pv;
          int row = g * 4 + j;
          pb[(row * 64 + key) ^ ((row & 7) << 3)] = bf1(pv);
        }
      }
      #pragma unroll
      for (int off = 1; off < 16; off <<= 1)
        #pragma unroll
        for (int j = 0; j < 4; ++j)
          lrow[j] += __shfl_xor(lrow[j], off, 64);
      #pragma unroll
      for (int j = 0; j < 4; ++j) lrun[u][j] = lrun[u][j] * alpha[j] + lrow[j];
      #pragma unroll
      for (int dt = 0; dt < 4; ++dt)
        #pragma unroll
        for (int j = 0; j < 4; ++j) oacc[u][dt][j] *= alpha[j];

      bf16x8 pf0 = ldsw8(pb, c,      g * 8);
      bf16x8 pf1 = ldsw8(pb, c, 32 + g * 8);
      #pragma unroll
      for (int dt = 0; dt < 4; ++dt) {
        bf16x8 v0 = ldsv8(vt, dt * 16 + c,      g * 8);
        bf16x8 v1 = ldsv8(vt, dt * 16 + c, 32 + g * 8);
        oacc[u][dt] = __builtin_amdgcn_mfma_f32_16x16x32_bf16(pf0, v0, oacc[u][dt], 0, 0, 0);
        oacc[u][dt] = __builtin_amdgcn_mfma_f32_16x16x32_bf16(pf1, v1, oacc[u][dt], 0, 0, 0);
      }
    }

    // convert + write NEXT tile into the other buffer (vmcnt waits land here,
    // after ~3000 cy of compute — HBM latency hidden; WAR safe per barrier above)
    if (pre) cvt_write(cur ^ 1);
    cur ^= 1;
  }

  // ---- epilogue: normalize and store [T,H,D] ----
  #pragma unroll
  for (int u = 0; u < 2; ++u) {
    float inv[4];
    #pragma unroll
    for (int j = 0; j < 4; ++j) inv[j] = 1.0f / lrun[u][j];
    #pragma unroll
    for (int dt = 0; dt < 4; ++dt) {
      #pragma unroll
      for (int j = 0; j < 4; ++j) {
        int rl = u * 64 + wv * 16 + g * 4 + j;
        if (rl < rows)
          out[((size_t)(row0 + rl) * HD + h) * DD + dt * 16 + c] = oacc[u][dt][j] * inv[j];
      }
    }
  }
}

extern "C" void kernel_launch(void* const* d_in, const int* in_sizes, int n_in,
                              void* d_out, int out_size, void* d_ws, size_t ws_size,
                              hipStream_t stream) {
  const float* q  = (const float*)d_in[0];
  const float* k  = (const float*)d_in[1];
  const float* v  = (const float*)d_in[2];
  const int*   cu = (const int*)d_in[3];
  int nseq = in_sizes[3] - 1;
  int T    = in_sizes[0] / (HD * DD);
  int nqt  = T / BQ + nseq;            // upper bound incl. partial tiles
  int nwg  = nqt * HD;
  fa_fwd<<<dim3(nwg), dim3(256), 0, stream>>>(q, k, v, cu, (float*)d_out, T, nseq, nqt);
}

// Round 18
// 131.135 us; speedup vs baseline: 1.1641x; 1.1641x over previous
//
#include <hip/hip_runtime.h>
#include <hip/hip_bf16.h>
#include <stdint.h>

typedef short  bf16x8 __attribute__((ext_vector_type(8)));
typedef float  f32x4  __attribute__((ext_vector_type(4)));
typedef unsigned short u16;

#define HD 16    // heads
#define DD 64    // head dim
#define BQ 128   // q rows per block (4 waves, 2 sub-tiles of 64: u-loop ILP, r12-validated)
#define BK 64    // keys per LDS tile

__device__ __forceinline__ u16 bf1(float a) {
  __hip_bfloat16 h = __float2bfloat16(a);
  union { __hip_bfloat16 h; u16 u; } cv; cv.h = h; return cv.u;
}
__device__ __forceinline__ uint32_t pk2(float a, float b) {
  __hip_bfloat162 h = __float22bfloat162_rn(make_float2(a, b)); // v_cvt_pk_bf16_f32
  union { __hip_bfloat162 h; uint32_t u; } cv; cv.h = h; return cv.u;
}

// K / P tiles: row-major [R][64] bf16, idx ^= (row&7)<<3
__device__ __forceinline__ bf16x8 ldsw8(const u16* base, int row, int col) {
  int idx = (row * 64 + col) ^ ((row & 7) << 3);
  return *reinterpret_cast<const bf16x8*>(base + idx);
}
// V^T tile: [d][key] bf16, idx ^= (((d>>2)^d)&7)<<3  (validated r11: conflicts 14x down)
__device__ __forceinline__ bf16x8 ldsv8(const u16* base, int d, int col) {
  int idx = (d * 64 + col) ^ ((((d >> 2) ^ d) & 7) << 3);
  return *reinterpret_cast<const bf16x8*>(base + idx);
}

__global__ __launch_bounds__(256) void fa_fwd(
    const float* __restrict__ q, const float* __restrict__ k,
    const float* __restrict__ v, const int* __restrict__ cu,
    float* __restrict__ out, int T, int nseq, int nqt)
{
  // single-buffered (32 KB total: stays at 2 blocks/CU — r17 lesson)
  __shared__ __align__(16) u16 sKhi[BK * DD];
  __shared__ __align__(16) u16 sKlo[BK * DD];
  __shared__ __align__(16) u16 sVt [DD * BK];
  __shared__ __align__(16) u16 sP  [4][16 * BK];

  // ---- XCD-chunked bijective remap (m204) ----
  const int nwg = nqt * HD;
  const int x8 = blockIdx.x & 7, mm = blockIdx.x >> 3;
  const int q8 = nwg >> 3, r8 = nwg & 7;
  const int wid = (x8 < r8 ? x8 * (q8 + 1) : r8 * (q8 + 1) + (x8 - r8) * q8) + mm;
  const int h    = wid / nqt;
  const int tile = wid - h * nqt;

  // ---- map tile -> (segment, local q-tile) ----
  int seg = -1, row0 = 0, sbeg = 0, send = 0;
  {
    int acc = 0;
    for (int s = 0; s < nseq; ++s) {
      int b = cu[s], e = cu[s + 1];
      int nt = (e - b + BQ - 1) >> 7;
      if (seg < 0 && tile < acc + nt) {
        seg = s;
        int local = tile - acc;
        row0 = b + local * BQ; sbeg = b; send = e;
      }
      acc += nt;
    }
  }
  if (seg < 0) return;
  const int rows = min(BQ, send - row0);

  const int tid  = threadIdx.x;
  const int wv   = tid >> 6;
  const int lane = tid & 63;
  const int g    = lane >> 4;
  const int c    = lane & 15;

  // ---- Q fragments for both sub-tiles, scale+log2e, hi/lo split ----
  const float SC = 8.0f * 1.4426950408889634f;
  bf16x8 qhi[2][2], qlo[2][2];
  #pragma unroll
  for (int u = 0; u < 2; ++u) {
    const int qrl = min(u * 64 + wv * 16 + c, rows - 1);
    const float* qp = q + ((size_t)h * T + (row0 + qrl)) * DD;
    #pragma unroll
    for (int w = 0; w < 2; ++w) {
      int d0 = w * 32 + g * 8;
      float4 a = *reinterpret_cast<const float4*>(qp + d0);
      float4 b = *reinterpret_cast<const float4*>(qp + d0 + 4);
      float f[8] = {a.x, a.y, a.z, a.w, b.x, b.y, b.z, b.w};
      #pragma unroll
      for (int i = 0; i < 8; ++i) {
        float s  = f[i] * SC;
        u16   hb = bf1(s);
        float hf = __uint_as_float(((uint32_t)hb) << 16);
        qhi[u][w][i] = (short)hb;
        qlo[u][w][i] = (short)bf1(s - hf);
      }
    }
  }

  // staging thread assignment (256 threads)
  const int kd0  = (tid & 15) * 4;
  const int kkey = tid >> 4;
  const int vdg  = tid & 15;
  const int vkb  = tid >> 4;

  float4 kraw[4], vrawA[2], vrawB[2];   // in-flight tile registers (T14 issue-early)

  auto issue_loads = [&](int kt0) {
    #pragma unroll
    for (int p = 0; p < 4; ++p) {
      int gk = kt0 + p * 16 + kkey; gk = gk < send ? gk : send - 1;
      kraw[p] = *reinterpret_cast<const float4*>(k + ((size_t)h * T + gk) * DD + kd0);
    }
    #pragma unroll
    for (int it = 0; it < 2; ++it) {
      int kp = it * 16 + vkb;
      int g0 = kt0 + 2 * kp;     g0 = g0 < send ? g0 : send - 1;
      int g1 = kt0 + 2 * kp + 1; g1 = g1 < send ? g1 : send - 1;
      vrawA[it] = *reinterpret_cast<const float4*>(v + ((size_t)h * T + g0) * DD + 4 * vdg);
      vrawB[it] = *reinterpret_cast<const float4*>(v + ((size_t)h * T + g1) * DD + 4 * vdg);
    }
  };
  auto cvt_write = [&]() {   // write-late: vmcnt waits land here, already covered by compute
    #pragma unroll
    for (int p = 0; p < 4; ++p) {
      int key = p * 16 + kkey;
      uint32_t h01 = pk2(kraw[p].x, kraw[p].y), h23 = pk2(kraw[p].z, kraw[p].w);
      float hf0 = __uint_as_float(h01 << 16);
      float hf1 = __uint_as_float(h01 & 0xffff0000u);
      float hf2 = __uint_as_float(h23 << 16);
      float hf3 = __uint_as_float(h23 & 0xffff0000u);
      uint32_t l01 = pk2(kraw[p].x - hf0, kraw[p].y - hf1);
      uint32_t l23 = pk2(kraw[p].z - hf2, kraw[p].w - hf3);
      int idx = (key * 64 + kd0) ^ ((key & 7) << 3);
      uint2 hh = {h01, h23}, ll = {l01, l23};
      *reinterpret_cast<uint2*>(sKhi + idx) = hh;
      *reinterpret_cast<uint2*>(sKlo + idx) = ll;
    }
    #pragma unroll
    for (int it = 0; it < 2; ++it) {
      int kp = it * 16 + vkb;
      float a[4] = {vrawA[it].x, vrawA[it].y, vrawA[it].z, vrawA[it].w};
      float bb[4] = {vrawB[it].x, vrawB[it].y, vrawB[it].z, vrawB[it].w};
      #pragma unroll
      for (int i = 0; i < 4; ++i) {
        int d   = 4 * vdg + i;
        int idx = (d * 64 + 2 * kp) ^ ((((d >> 2) ^ d) & 7) << 3);
        *reinterpret_cast<uint32_t*>(sVt + idx) = pk2(a[i], bb[i]);
      }
    }
  };

  f32x4 zero4 = {0.f, 0.f, 0.f, 0.f};
  f32x4 oacc[2][4];
  float mrun[2][4], lrun[2][4];
  #pragma unroll
  for (int u = 0; u < 2; ++u) {
    #pragma unroll
    for (int dt = 0; dt < 4; ++dt) oacc[u][dt] = zero4;
    #pragma unroll
    for (int j = 0; j < 4; ++j) { mrun[u][j] = -1e30f; lrun[u][j] = 0.f; }
  }

  const int nt = (send - sbeg + BK - 1) >> 6;

  issue_loads(sbeg);   // prologue: tile-0 loads in flight

  for (int t = 0; t < nt; ++t) {
    const int kt0 = sbeg + t * BK;
    __syncthreads();     // previous tile's compute done; LDS free
    cvt_write();         // tile-t regs -> LDS (loads long since landed)
    __syncthreads();     // LDS tile ready
    if (t + 1 < nt) issue_loads(kt0 + BK);   // HBM latency hides under compute below

    #pragma unroll
    for (int u = 0; u < 2; ++u) {
      f32x4 sacc[4];
      #pragma unroll
      for (int kt = 0; kt < 4; ++kt) sacc[kt] = zero4;
      #pragma unroll
      for (int kt = 0; kt < 4; ++kt) {
        int krow = kt * 16 + c;
        bf16x8 kh0 = ldsw8(sKhi, krow,      g * 8);
        bf16x8 kh1 = ldsw8(sKhi, krow, 32 + g * 8);
        bf16x8 kl0 = ldsw8(sKlo, krow,      g * 8);
        bf16x8 kl1 = ldsw8(sKlo, krow, 32 + g * 8);
        sacc[kt] = __builtin_amdgcn_mfma_f32_16x16x32_bf16(qhi[u][0], kh0, sacc[kt], 0, 0, 0);
        sacc[kt] = __builtin_amdgcn_mfma_f32_16x16x32_bf16(qhi[u][1], kh1, sacc[kt], 0, 0, 0);
        sacc[kt] = __builtin_amdgcn_mfma_f32_16x16x32_bf16(qlo[u][0], kh0, sacc[kt], 0, 0, 0);
        sacc[kt] = __builtin_amdgcn_mfma_f32_16x16x32_bf16(qlo[u][1], kh1, sacc[kt], 0, 0, 0);
        sacc[kt] = __builtin_amdgcn_mfma_f32_16x16x32_bf16(qhi[u][0], kl0, sacc[kt], 0, 0, 0);
        sacc[kt] = __builtin_amdgcn_mfma_f32_16x16x32_bf16(qhi[u][1], kl1, sacc[kt], 0, 0, 0);
      }

      if (kt0 + BK > send) {
        #pragma unroll
        for (int kt = 0; kt < 4; ++kt) {
          int gk = kt0 + kt * 16 + c;
          if (gk >= send) {
            sacc[kt][0] = -3.0e38f; sacc[kt][1] = -3.0e38f;
            sacc[kt][2] = -3.0e38f; sacc[kt][3] = -3.0e38f;
          }
        }
      }

      float mrow[4];
      #pragma unroll
      for (int j = 0; j < 4; ++j)
        mrow[j] = fmaxf(fmaxf(sacc[0][j], sacc[1][j]), fmaxf(sacc[2][j], sacc[3][j]));
      #pragma unroll
      for (int off = 1; off < 16; off <<= 1)
        #pragma unroll
        for (int j = 0; j < 4; ++j)
          mrow[j] = fmaxf(mrow[j], __shfl_xor(mrow[j], off, 64));

      float alpha[4];
      #pragma unroll
      for (int j = 0; j < 4; ++j) {
        float mn = fmaxf(mrun[u][j], mrow[j]);
        alpha[j] = exp2f(mrun[u][j] - mn);
        mrun[u][j] = mn;
      }

      float lrow[4] = {0.f, 0.f, 0.f, 0.f};
      u16* pb = sP[wv];
      #pragma unroll
      for (int kt = 0; kt < 4; ++kt) {
        int key = kt * 16 + c;
        #pragma unroll
        for (int j = 0; j < 4; ++j) {
          float pv = exp2f(sacc[kt][j] - mrun[u][j]);
          lrow[j] += pv;
          int row = g * 4 + j;
          pb[(row * 64 + key) ^ ((row & 7) << 3)] = bf1(pv);
        }
      }
      #pragma unroll
      for (int off = 1; off < 16; off <<= 1)
        #pragma unroll
        for (int j = 0; j < 4; ++j)
          lrow[j] += __shfl_xor(lrow[j], off, 64);
      #pragma unroll
      for (int j = 0; j < 4; ++j) lrun[u][j] = lrun[u][j] * alpha[j] + lrow[j];
      #pragma unroll
      for (int dt = 0; dt < 4; ++dt)
        #pragma unroll
        for (int j = 0; j < 4; ++j) oacc[u][dt][j] *= alpha[j];

      bf16x8 pf0 = ldsw8(pb, c,      g * 8);
      bf16x8 pf1 = ldsw8(pb, c, 32 + g * 8);
      #pragma unroll
      for (int dt = 0; dt < 4; ++dt) {
        bf16x8 v0 = ldsv8(sVt, dt * 16 + c,      g * 8);
        bf16x8 v1 = ldsv8(sVt, dt * 16 + c, 32 + g * 8);
        oacc[u][dt] = __builtin_amdgcn_mfma_f32_16x16x32_bf16(pf0, v0, oacc[u][dt], 0, 0, 0);
        oacc[u][dt] = __builtin_amdgcn_mfma_f32_16x16x32_bf16(pf1, v1, oacc[u][dt], 0, 0, 0);
      }
    }
  }

  // ---- epilogue: normalize and store [T,H,D] ----
  #pragma unroll
  for (int u = 0; u < 2; ++u) {
    float inv[4];
    #pragma unroll
    for (int j = 0; j < 4; ++j) inv[j] = 1.0f / lrun[u][j];
    #pragma unroll
    for (int dt = 0; dt < 4; ++dt) {
      #pragma unroll
      for (int j = 0; j < 4; ++j) {
        int rl = u * 64 + wv * 16 + g * 4 + j;
        if (rl < rows)
          out[((size_t)(row0 + rl) * HD + h) * DD + dt * 16 + c] = oacc[u][dt][j] * inv[j];
      }
    }
  }
}

extern "C" void kernel_launch(void* const* d_in, const int* in_sizes, int n_in,
                              void* d_out, int out_size, void* d_ws, size_t ws_size,
                              hipStream_t stream) {
  const float* q  = (const float*)d_in[0];
  const float* k  = (const float*)d_in[1];
  const float* v  = (const float*)d_in[2];
  const int*   cu = (const int*)d_in[3];
  int nseq = in_sizes[3] - 1;
  int T    = in_sizes[0] / (HD * DD);
  int nqt  = T / BQ + nseq;            // upper bound incl. partial tiles
  int nwg  = nqt * HD;
  fa_fwd<<<dim3(nwg), dim3(256), 0, stream>>>(q, k, v, cu, (float*)d_out, T, nseq, nqt);
}